// Round 3
// baseline (125753.711 us; speedup 1.0000x reference)
//
#include <hip/hip_runtime.h>
#include <math.h>

// B=32, T=512, IDIM=512, ODIM=80, L=256, DUNITS=1024, ATT=128, ACH=10, AK=31, PRE=256, POST=512
typedef unsigned long long ull;

__device__ __forceinline__ float sigm(float x){ return 1.0f/(1.0f+__expf(-x)); }
__device__ __forceinline__ float tanh_fast(float x){
  float e = __expf(2.0f*x);
  return 1.0f - 2.0f/(e + 1.0f);
}

// Coherent (MALL-level) access helpers: relaxed agent-scope atomics emit sc1
// loads/stores that bypass the non-coherent per-XCD L2. No cache maintenance.
__device__ __forceinline__ float ldc(const float* p){
  return __hip_atomic_load(p, __ATOMIC_RELAXED, __HIP_MEMORY_SCOPE_AGENT);
}
__device__ __forceinline__ void stc(float* p, float v){
  __hip_atomic_store(p, v, __ATOMIC_RELAXED, __HIP_MEMORY_SCOPE_AGENT);
}
__device__ __forceinline__ ull ldc8(const ull* p){
  return __hip_atomic_load(p, __ATOMIC_RELAXED, __HIP_MEMORY_SCOPE_AGENT);
}

// ---------------- workspace layout (floats) ----------------
#define OFF_ENC   0          // 2097152  enc_proj (B,T,ATT)
#define OFF_AWG   2097152    // 16384    aw (B,T)
#define OFF_XC    2113536    // 24576    xc [k][b], k<768
#define OFF_Z0T   2138112    // 32768    z0 [u][b]
#define OFF_Z1T   2170880    // 32768
#define OFF_DEC   2203648    // 4096     dec [b][a]
#define OFF_OUTS  2207744    // 655360   outs_ws (B,80,256)
#define OFF_PN1   2863104    // 4194304
#define OFF_PN2   7057408    // 4194304
#define OFF_BSC   11251712   // 512
#define OFF_BSH   11252224   // 512
#define OFF_BAR   11252736   // 256 uints

// ---------------- shared carve (floats) ----------------
#define ST_X     0        // 16384 (64KB) stage / reduce / scratch
#define ST_G0    16384    // 512
#define ST_G1    16896    // 512
#define ST_AWP   17408    // 544  aw padded by 15 both sides
#define ST_WLT   17952    // 2048 [a][16]: c0..9 wloc, 10 gvec, 11 dec
#define ST_LOCK  20000    // 320  [c][32]
#define ST_RED   20320    // 16
#define ST_OUT   20336    // 96
#define ST_H1    20432    // 256
#define ST_CL    20688    // 256: c0 at +0, c1 at +128
#define SMEM_FLOATS 20944

__global__ void k_init(float* __restrict__ ws, const int* __restrict__ ylens,
                       float* __restrict__ d_out) {
  int i = threadIdx.x;
  unsigned* bar = (unsigned*)(ws + OFF_BAR);
  if (i < 256) bar[i] = 0u;
  if (i < 32) d_out[663552 + i] = (float)ylens[i];
}

// ---------------- enc_proj = hs @ w_enc + b_enc ----------------
__global__ void k_encproj(const float* __restrict__ hs, const float* __restrict__ w_enc,
                          const float* __restrict__ b_enc, float* __restrict__ enc_proj) {
  __shared__ float hsl[16*512];
  int b = blockIdx.x, t0 = blockIdx.y*16;
  int tid = threadIdx.x;  // 256
  for (int i = tid; i < 16*512; i += 256)
    hsl[i] = hs[(size_t)(b*512 + t0 + (i>>9))*512 + (i&511)];
  __syncthreads();
  int a = tid & 127, tq = tid >> 7;
  float acc[8];
  #pragma unroll
  for (int u=0;u<8;++u) acc[u]=0.f;
  for (int d=0; d<512; ++d) {
    float w = w_enc[d*128 + a];
    #pragma unroll
    for (int u=0;u<8;++u) acc[u] += hsl[(tq*8+u)*512 + d]*w;
  }
  float be = b_enc[a];
  #pragma unroll
  for (int u=0;u<8;++u)
    enc_proj[(size_t)(b*512 + t0 + tq*8 + u)*128 + a] = acc[u] + be;
}

// ---------------- grid barrier: no fences, sc1 traffic only ----------------
__device__ __forceinline__ void gsync(unsigned* bar, unsigned gen) {
  __syncthreads();
  asm volatile("s_waitcnt vmcnt(0)" ::: "memory");
  if (threadIdx.x == 0)
    __hip_atomic_fetch_add(&bar[(blockIdx.x & 7)*32], 1u,
                           __ATOMIC_RELAXED, __HIP_MEMORY_SCOPE_AGENT);
  if (threadIdx.x < 8) {
    unsigned tgt = gen*32u;
    while (__hip_atomic_load(&bar[threadIdx.x*32],
                             __ATOMIC_RELAXED, __HIP_MEMORY_SCOPE_AGENT) < tgt)
      __builtin_amdgcn_s_sleep(1);
  }
  __syncthreads();
}

// stage kcount*32 floats from coherent src[k][b] (at k0) into S_x
__device__ __forceinline__ void stage_x(const float* __restrict__ src, int k0, int kcount,
                                        float* S_x, int tid) {
  const ull* s8 = (const ull*)(src + k0*32);
  ull* d8 = (ull*)S_x;
  for (int i = tid; i < kcount*16; i += 512) d8[i] = ldc8(s8 + i);
}

#define GROW(r, av) \
  acc[r][0] += av.x*x0.x + av.y*x1.x + av.z*x2.x + av.w*x3.x; \
  acc[r][1] += av.x*x0.y + av.y*x1.y + av.z*x2.y + av.w*x3.y; \
  acc[r][2] += av.x*x0.z + av.y*x1.z + av.z*x2.z + av.w*x3.z; \
  acc[r][3] += av.x*x0.w + av.y*x1.w + av.z*x2.w + av.w*x3.w;

// block owns rows j_global = gate*1024 + bid*4 + uo (gate=rq, uo=ri)
__device__ __forceinline__ void gemm_acc(const float* __restrict__ W, int K, int k0,
                                         int kcount, const float* S_x,
                                         float (*acc)[4], int rq, int bq, int ks, int bid) {
  int kslice = kcount >> 4;
  int kl0 = ks * kslice;
  const float* w0 = W + (size_t)(rq*1024 + bid*4)*K + (k0 + kl0);
  const float* w1 = w0 + K;
  const float* w2 = w1 + K;
  const float* w3 = w2 + K;
  const float* xp = S_x + kl0*32 + bq*4;
  for (int kk = 0; kk < kslice; kk += 4) {
    float4 a0 = *(const float4*)(w0 + kk);
    float4 a1 = *(const float4*)(w1 + kk);
    float4 a2 = *(const float4*)(w2 + kk);
    float4 a3 = *(const float4*)(w3 + kk);
    float4 x0 = *(const float4*)(xp + (kk+0)*32);
    float4 x1 = *(const float4*)(xp + (kk+1)*32);
    float4 x2 = *(const float4*)(xp + (kk+2)*32);
    float4 x3 = *(const float4*)(xp + (kk+3)*32);
    GROW(0, a0) GROW(1, a1) GROW(2, a2) GROW(3, a3)
  }
}

#define ZACC { for(int _r=0;_r<4;++_r) for(int _b=0;_b<4;++_b) acc[_r][_b]=0.f; }

// write partials + reduce over 16 k-slices -> per-thread scalar
__device__ __forceinline__ float reduce_part(float (*acc)[4], float* S_x,
                                             int rq, int bq, int ks, int tid) {
  __syncthreads();
  #pragma unroll
  for (int ri = 0; ri < 4; ++ri)
    #pragma unroll
    for (int bi = 0; bi < 4; ++bi)
      S_x[((rq*4+ri)*32 + bq*4+bi)*17 + ks] = acc[ri][bi];
  __syncthreads();
  float g = 0.f;
  #pragma unroll
  for (int q = 0; q < 16; ++q) g += S_x[tid*17 + q];
  return g;
}

__global__ __launch_bounds__(512, 2) void k_scan(
    const float* __restrict__ hs, const int* __restrict__ hlens,
    const float* __restrict__ loc_k, const float* __restrict__ w_loc,
    const float* __restrict__ gvec, const float* __restrict__ w_dec,
    const float* __restrict__ pre_w1, const float* __restrict__ pre_b1,
    const float* __restrict__ pre_w2, const float* __restrict__ pre_b2,
    const float* __restrict__ l0_wih, const float* __restrict__ l0_whh,
    const float* __restrict__ l0_b, const float* __restrict__ l1_wih,
    const float* __restrict__ l1_whh, const float* __restrict__ l1_b,
    const float* __restrict__ feat_w, const float* __restrict__ feat_b,
    const float* __restrict__ prob_w, const float* __restrict__ prob_b,
    float* __restrict__ ws, float* __restrict__ probs_out) {
  extern __shared__ float S[];
  int tid = threadIdx.x, bid = blockIdx.x;
  int tile = tid & 31, ks = tid >> 5;
  int rq = tile >> 3, bq = tile & 7;

  float* enc_proj = ws + OFF_ENC;
  float* aw_g = ws + OFF_AWG;
  float* xc   = ws + OFF_XC;
  float* z0T  = ws + OFF_Z0T;
  float* z1T  = ws + OFF_Z1T;
  float* decg = ws + OFF_DEC;
  float* outs_ws = ws + OFF_OUTS;
  unsigned* bar = (unsigned*)(ws + OFF_BAR);
  float* S_x = S + ST_X;

  // ---- per-block LDS init ----
  if (tid < 256) S[ST_CL + tid] = 0.f;
  if (bid < 32) {
    int b = bid;
    int hl = hlens[b];
    float inv = 1.f/(float)hl;
    for (int i = tid; i < 544; i += 512) S[ST_AWP + i] = 0.f;
    __syncthreads();
    S[ST_AWP + 15 + tid] = (tid < hl) ? inv : 0.f;
    if (tid < 128) {
      #pragma unroll
      for (int c = 0; c < 10; ++c) S[ST_WLT + tid*16 + c] = w_loc[c*128 + tid];
      S[ST_WLT + tid*16 + 10] = gvec[tid];
    }
    if (tid < 310) S[ST_LOCK + (tid/31)*32 + (tid%31)] = loc_k[tid];
  }
  __syncthreads();

  unsigned gen = 0;

  for (int s = 0; s < 256; ++s) {
    // ===================== P1 =====================
    if (s == 0) {
      S[ST_G0 + tid] = 0.f;
      S[ST_G1 + tid] = 0.f;
    } else {
      float acc[4][4]; ZACC;
      for (int c = 0; c < 2; ++c) {
        __syncthreads();
        stage_x(z0T, c*512, 512, S_x, tid);
        __syncthreads();
        gemm_acc(l0_whh, 1024, c*512, 512, S_x, acc, rq, bq, ks, bid);
      }
      S[ST_G0 + tid] = reduce_part(acc, S_x, rq, bq, ks, tid);
      ZACC;
      float oacc = 0.f;
      for (int c = 0; c < 2; ++c) {
        __syncthreads();
        stage_x(z1T, c*512, 512, S_x, tid);
        __syncthreads();
        gemm_acc(l1_whh, 1024, c*512, 512, S_x, acc, rq, bq, ks, bid);
        if (bid >= 32 && bid < 64) {  // out/prob GEMV partial from staged z1
          int b = bid - 32, o = tid & 127, th = tid >> 7;
          if (o < 81) {
            for (int kk = th*128; kk < th*128 + 128; ++kk) {
              float xv = S_x[kk*32 + b];
              oacc += xv * (o < 80 ? feat_w[(size_t)(c*512+kk)*80 + o] : prob_w[c*512+kk]);
            }
          }
        }
      }
      S[ST_G1 + tid] = reduce_part(acc, S_x, rq, bq, ks, tid);
      if (bid >= 32 && bid < 64) {
        int b = bid - 32, o = tid & 127, th = tid >> 7;
        __syncthreads();
        if (o < 81) S_x[o*4 + th] = oacc;
        __syncthreads();
        if (tid < 81) {
          float ov = S_x[tid*4] + S_x[tid*4+1] + S_x[tid*4+2] + S_x[tid*4+3];
          if (tid < 80) {
            ov += feat_b[tid];
            S[ST_OUT + tid] = ov;
            outs_ws[(b*80 + tid)*256 + (s-1)] = ov;
          } else {
            probs_out[b*256 + (s-1)] = ov + prob_b[0];
          }
        }
      }
    }
    __syncthreads();
    if (s == 0 && bid >= 32 && bid < 64) {
      if (tid < 80) S[ST_OUT + tid] = feat_b[tid];
    }
    // ---- att blocks: energies + softmax -> aw(s) ----
    if (bid < 32) {
      int b = bid;
      int hl = hlens[b];
      if (tid < 128) S[ST_WLT + tid*16 + 11] = (s == 0) ? 0.f : ldc(&decg[b*128 + tid]);
      __syncthreads();
      int t = tid;
      float loc_c[10];
      #pragma unroll
      for (int c = 0; c < 10; ++c) {
        float sacc = 0.f;
        #pragma unroll
        for (int k = 0; k < 31; ++k) sacc += S[ST_AWP + t + k]*S[ST_LOCK + c*32 + k];
        loc_c[c] = sacc;
      }
      float e_t;
      if (t < hl) {
        const float4* ep = (const float4*)(enc_proj + ((size_t)b*512 + t)*128);
        float ea = 0.f;
        for (int a4 = 0; a4 < 32; ++a4) {
          float4 ev = ep[a4];
          float evv[4] = {ev.x, ev.y, ev.z, ev.w};
          #pragma unroll
          for (int q = 0; q < 4; ++q) {
            int a = a4*4 + q;
            const float* wl = &S[ST_WLT + a*16];
            float4 wa = *(const float4*)wl;
            float4 wb = *(const float4*)(wl+4);
            float4 wc = *(const float4*)(wl+8);
            float arg = evv[q] + wc.w;
            arg += loc_c[0]*wa.x + loc_c[1]*wa.y + loc_c[2]*wa.z + loc_c[3]*wa.w;
            arg += loc_c[4]*wb.x + loc_c[5]*wb.y + loc_c[6]*wb.z + loc_c[7]*wb.w;
            arg += loc_c[8]*wc.x + loc_c[9]*wc.y;
            ea += wc.z * tanh_fast(arg);
          }
        }
        e_t = ea;
      } else e_t = -1e30f;
      float m = e_t;
      #pragma unroll
      for (int off = 32; off; off >>= 1) m = fmaxf(m, __shfl_xor(m, off));
      if ((tid & 63) == 0) S[ST_RED + (tid>>6)] = m;
      __syncthreads();
      m = S[ST_RED];
      #pragma unroll
      for (int w = 1; w < 8; ++w) m = fmaxf(m, S[ST_RED + w]);
      float p = __expf(e_t - m);
      float sum = p;
      #pragma unroll
      for (int off = 32; off; off >>= 1) sum += __shfl_xor(sum, off);
      if ((tid & 63) == 0) S[ST_RED + 8 + (tid>>6)] = sum;
      __syncthreads();
      sum = S[ST_RED + 8];
      #pragma unroll
      for (int w = 1; w < 8; ++w) sum += S[ST_RED + 8 + w];
      float awv = p / sum;
      S[ST_AWP + 15 + t] = awv;
      stc(&aw_g[b*512 + t], awv);
    }
    // ---- out blocks: prenet ----
    if (bid >= 32 && bid < 64) {
      int b = bid - 32;
      __syncthreads();
      if (tid < 256) {
        float h = pre_b1[tid];
        for (int k = 0; k < 80; ++k) h += S[ST_OUT + k]*pre_w1[k*256 + tid];
        S[ST_H1 + tid] = fmaxf(h, 0.f);
      }
      __syncthreads();
      if (tid < 256) {
        float h = pre_b2[tid];
        for (int k = 0; k < 256; ++k) h += S[ST_H1 + k]*pre_w2[k*256 + tid];
        stc(&xc[(512 + tid)*32 + b], fmaxf(h, 0.f));
      }
    }
    gen++; gsync(bar, gen);

    // ===================== P2: context =====================
    {
      int b = bid >> 3, dc = bid & 7;
      if (tid < 256) ((ull*)S_x)[tid] = ldc8((const ull*)(aw_g + b*512) + tid);
      __syncthreads();
      int di = tid & 63, th = tid >> 6;
      const float* hp = hs + ((size_t)b*512 + th*64)*512 + dc*64 + di;
      float cacc = 0.f;
      for (int t2 = 0; t2 < 64; ++t2) cacc += S_x[th*64 + t2] * hp[(size_t)t2*512];
      S_x[512 + th*64 + di] = cacc;
      __syncthreads();
      if (tid < 64) {
        float v = 0.f;
        #pragma unroll
        for (int w = 0; w < 8; ++w) v += S_x[512 + w*64 + tid];
        stc(&xc[(dc*64 + tid)*32 + b], v);
      }
    }
    gen++; gsync(bar, gen);

    // ===================== P3: LSTM0 x-part + gates =====================
    {
      float acc[4][4]; ZACC;
      __syncthreads();
      stage_x(xc, 0, 512, S_x, tid);
      __syncthreads();
      gemm_acc(l0_wih, 768, 0, 512, S_x, acc, rq, bq, ks, bid);
      __syncthreads();
      stage_x(xc, 512, 256, S_x, tid);
      __syncthreads();
      gemm_acc(l0_wih, 768, 512, 256, S_x, acc, rq, bq, ks, bid);
      float g = reduce_part(acc, S_x, rq, bq, ks, tid);
      int jl = tid >> 5, gate = jl >> 2, uo = jl & 3;
      g += S[ST_G0 + tid] + l0_b[gate*1024 + bid*4 + uo];
      S[ST_G0 + tid] = g;
      __syncthreads();
      if (tid < 128) {
        int u2 = tid >> 5, b2 = tid & 31;
        float gi = S[ST_G0 + (0*4+u2)*32 + b2];
        float gf = S[ST_G0 + (1*4+u2)*32 + b2];
        float gg = S[ST_G0 + (2*4+u2)*32 + b2];
        float go = S[ST_G0 + (3*4+u2)*32 + b2];
        float co = S[ST_CL + u2*32 + b2];
        float cn = sigm(gf)*co + sigm(gi)*tanh_fast(gg);
        S[ST_CL + u2*32 + b2] = cn;
        stc(&z0T[(bid*4 + u2)*32 + b2], sigm(go)*tanh_fast(cn));
      }
    }
    gen++; gsync(bar, gen);

    // ===================== P4: LSTM1 x-part + gates + dec =====================
    {
      float acc[4][4]; ZACC;
      for (int c = 0; c < 2; ++c) {
        __syncthreads();
        stage_x(z0T, c*512, 512, S_x, tid);
        __syncthreads();
        gemm_acc(l1_wih, 1024, c*512, 512, S_x, acc, rq, bq, ks, bid);
      }
      float g = reduce_part(acc, S_x, rq, bq, ks, tid);
      int jl = tid >> 5, gate = jl >> 2, uo = jl & 3;
      g += S[ST_G1 + tid] + l1_b[gate*1024 + bid*4 + uo];
      S[ST_G1 + tid] = g;
      __syncthreads();
      if (tid < 128) {
        int u2 = tid >> 5, b2 = tid & 31;
        float gi = S[ST_G1 + (0*4+u2)*32 + b2];
        float gf = S[ST_G1 + (1*4+u2)*32 + b2];
        float gg = S[ST_G1 + (2*4+u2)*32 + b2];
        float go = S[ST_G1 + (3*4+u2)*32 + b2];
        float co = S[ST_CL + 128 + u2*32 + b2];
        float cn = sigm(gf)*co + sigm(gi)*tanh_fast(gg);
        S[ST_CL + 128 + u2*32 + b2] = cn;
        stc(&z1T[(bid*4 + u2)*32 + b2], sigm(go)*tanh_fast(cn));
      }
      if (bid >= 224) {  // dec(s+1) = z0(s) @ w_dec
        int b = bid - 224;
        __syncthreads();
        S_x[tid] = ldc(&z0T[tid*32 + b]);
        S_x[512 + tid] = ldc(&z0T[(512 + tid)*32 + b]);
        __syncthreads();
        int a = tid & 127, kq = tid >> 7;
        float da = 0.f;
        for (int k = kq*256; k < kq*256 + 256; ++k) da += S_x[k]*w_dec[k*128 + a];
        __syncthreads();
        S_x[1024 + kq*128 + a] = da;
        __syncthreads();
        if (tid < 128)
          stc(&decg[b*128 + tid],
              S_x[1024+tid] + S_x[1152+tid] + S_x[1280+tid] + S_x[1408+tid]);
      }
    }
    gen++; gsync(bar, gen);
  }

  // ===== final out/prob (index 255) from z1(255) =====
  if (bid >= 32 && bid < 64) {
    int b = bid - 32;
    S_x[tid] = ldc(&z1T[tid*32 + b]);
    S_x[512 + tid] = ldc(&z1T[(512 + tid)*32 + b]);
    __syncthreads();
    int o = tid & 127, kq = tid >> 7;
    float fa = 0.f;
    if (o < 81) {
      for (int k = kq*256; k < kq*256 + 256; ++k)
        fa += S_x[k] * (o < 80 ? feat_w[(size_t)k*80 + o] : prob_w[k]);
    }
    __syncthreads();
    S_x[1024 + kq*128 + o] = fa;
    __syncthreads();
    if (tid < 81) {
      float ov = S_x[1024+tid] + S_x[1152+tid] + S_x[1280+tid] + S_x[1408+tid];
      if (tid < 80) outs_ws[(b*80 + tid)*256 + 255] = ov + feat_b[tid];
      else probs_out[b*256 + 255] = ov + prob_b[0];
    }
  }
}

// ---------------- postnet conv1d (k=5, pad=2) ----------------
__global__ void k_conv(const float* __restrict__ in, const float* __restrict__ wk,
                       int CI, int CO, float* __restrict__ out,
                       const float* __restrict__ resid, float* __restrict__ final_out) {
  int b = blockIdx.x, coT = blockIdx.y, lT = blockIdx.z;
  int l0 = lT*64;
  int tid = threadIdx.x;
  int lq = tid & 15, coq = tid >> 4;
  __shared__ float xs[16*68];
  __shared__ float wt[64*81];
  float acc[4][4];
  #pragma unroll
  for (int m = 0; m < 4; ++m)
    #pragma unroll
    for (int li = 0; li < 4; ++li) acc[m][li] = 0.f;
  int coBase = coT*64 + coq*4;
  for (int cc0 = 0; cc0 < CI; cc0 += 16) {
    __syncthreads();
    for (int i = tid; i < 16*68; i += 256) {
      int ci = i/68, pos = i - ci*68;
      int gl = l0 - 2 + pos;
      xs[i] = (gl >= 0 && gl < 256) ? in[((size_t)b*CI + cc0 + ci)*256 + gl] : 0.f;
    }
    for (int i = tid; i < 64*80; i += 256) {
      int co_i = i/80, rem = i - co_i*80;
      int cog = coT*64 + co_i;
      float w = (cog < CO) ? wk[(size_t)cog*CI*5 + (size_t)cc0*5 + rem] : 0.f;
      wt[co_i*81 + rem] = w;
    }
    __syncthreads();
    #pragma unroll 2
    for (int ci = 0; ci < 16; ++ci) {
      float4 xa = *(const float4*)&xs[ci*68 + lq*4];
      float4 xb = *(const float4*)&xs[ci*68 + lq*4 + 4];
      float x8[8] = {xa.x, xa.y, xa.z, xa.w, xb.x, xb.y, xb.z, xb.w};
      #pragma unroll
      for (int kk = 0; kk < 5; ++kk) {
        float w0 = wt[(coq*4+0)*81 + ci*5 + kk];
        float w1 = wt[(coq*4+1)*81 + ci*5 + kk];
        float w2 = wt[(coq*4+2)*81 + ci*5 + kk];
        float w3 = wt[(coq*4+3)*81 + ci*5 + kk];
        #pragma unroll
        for (int li = 0; li < 4; ++li) {
          float xv = x8[kk + li];
          acc[0][li] += w0*xv; acc[1][li] += w1*xv;
          acc[2][li] += w2*xv; acc[3][li] += w3*xv;
        }
      }
    }
  }
  if (final_out) {
    #pragma unroll
    for (int m = 0; m < 4; ++m) {
      int co = coBase + m;
      if (co < CO) {
        #pragma unroll
        for (int li = 0; li < 4; ++li) {
          int l = l0 + lq*4 + li;
          final_out[(size_t)(b*256 + l)*80 + co] =
              acc[m][li] + resid[((size_t)b*80 + co)*256 + l];
        }
      }
    }
  } else {
    #pragma unroll
    for (int m = 0; m < 4; ++m) {
      int co = coBase + m;
      if (co < CO) {
        float4 v = {acc[m][0], acc[m][1], acc[m][2], acc[m][3]};
        *(float4*)&out[((size_t)b*CO + co)*256 + l0 + lq*4] = v;
      }
    }
  }
}

__global__ void k_bnstats(const float* __restrict__ x, const float* __restrict__ g,
                          const float* __restrict__ bt, float* __restrict__ scale,
                          float* __restrict__ shift) {
  int c = blockIdx.x;
  int tid = threadIdx.x;  // 256
  float s = 0.f, s2 = 0.f;
  for (int i = tid; i < 8192; i += 256) {
    int bb = i >> 8, l = i & 255;
    float v = x[((size_t)bb*512 + c)*256 + l];
    s += v; s2 += v*v;
  }
  __shared__ float rs[256], rs2[256];
  rs[tid] = s; rs2[tid] = s2;
  __syncthreads();
  for (int st = 128; st; st >>= 1) {
    if (tid < st) { rs[tid] += rs[tid + st]; rs2[tid] += rs2[tid + st]; }
    __syncthreads();
  }
  if (tid == 0) {
    float m = rs[0]/8192.f;
    float var = rs2[0]/8192.f - m*m;
    float inv = rsqrtf(var + 1e-5f);
    float sc = g[c]*inv;
    scale[c] = sc;
    shift[c] = bt[c] - m*sc;
  }
}

__global__ void k_bnapply(float* __restrict__ x, const float* __restrict__ scale,
                          const float* __restrict__ shift) {
  int i = blockIdx.x*256 + threadIdx.x;
  if (i < 32*512*256) {
    int c = (i >> 8) & 511;
    x[i] = tanhf(scale[c]*x[i] + shift[c]);
  }
}

// ---------------- launcher ----------------
extern "C" void kernel_launch(void* const* d_in, const int* in_sizes, int n_in,
                              void* d_out, int out_size, void* d_ws, size_t ws_size,
                              hipStream_t stream) {
  const float* hs       = (const float*)d_in[0];
  const int*   hlens    = (const int*)d_in[1];
  const int*   ylens    = (const int*)d_in[3];
  const float* w_enc    = (const float*)d_in[4];
  const float* b_enc    = (const float*)d_in[5];
  const float* w_dec    = (const float*)d_in[6];
  const float* loc_k    = (const float*)d_in[7];
  const float* w_loc    = (const float*)d_in[8];
  const float* gvec     = (const float*)d_in[9];
  const float* pre_w1   = (const float*)d_in[10];
  const float* pre_b1   = (const float*)d_in[11];
  const float* pre_w2   = (const float*)d_in[12];
  const float* pre_b2   = (const float*)d_in[13];
  const float* l0_wih   = (const float*)d_in[14];
  const float* l0_whh   = (const float*)d_in[15];
  const float* l0_b     = (const float*)d_in[16];
  const float* l1_wih   = (const float*)d_in[17];
  const float* l1_whh   = (const float*)d_in[18];
  const float* l1_b     = (const float*)d_in[19];
  const float* feat_w   = (const float*)d_in[20];
  const float* feat_b   = (const float*)d_in[21];
  const float* prob_w   = (const float*)d_in[22];
  const float* prob_b   = (const float*)d_in[23];
  const float* post_k1  = (const float*)d_in[24];
  const float* post_k2  = (const float*)d_in[25];
  const float* post_k3  = (const float*)d_in[26];
  const float* post_k4  = (const float*)d_in[27];
  const float* post_k5  = (const float*)d_in[28];
  const float* bn_g1 = (const float*)d_in[29]; const float* bn_b1 = (const float*)d_in[30];
  const float* bn_g2 = (const float*)d_in[31]; const float* bn_b2 = (const float*)d_in[32];
  const float* bn_g3 = (const float*)d_in[33]; const float* bn_b3 = (const float*)d_in[34];
  const float* bn_g4 = (const float*)d_in[35]; const float* bn_b4 = (const float*)d_in[36];

  float* ws = (float*)d_ws;
  float* enc_proj = ws + OFF_ENC;
  float* outs_ws  = ws + OFF_OUTS;
  float* pn1      = ws + OFF_PN1;
  float* pn2      = ws + OFF_PN2;
  float* bsc      = ws + OFF_BSC;
  float* bsh      = ws + OFF_BSH;

  float* outp  = (float*)d_out;            // outs (B,L,80)
  float* probp = outp + 655360;            // probs (B,L)

  k_init<<<1, 256, 0, stream>>>(ws, ylens, outp);
  k_encproj<<<dim3(32, 32), 256, 0, stream>>>(hs, w_enc, b_enc, enc_proj);

  k_scan<<<256, 512, SMEM_FLOATS*4, stream>>>(hs, hlens, loc_k, w_loc, gvec, w_dec,
                                  pre_w1, pre_b1, pre_w2, pre_b2,
                                  l0_wih, l0_whh, l0_b, l1_wih, l1_whh, l1_b,
                                  feat_w, feat_b, prob_w, prob_b,
                                  ws, probp);

  // postnet
  k_conv<<<dim3(32, 8, 4), 256, 0, stream>>>(outs_ws, post_k1, 80, 512, pn1, nullptr, nullptr);
  k_bnstats<<<512, 256, 0, stream>>>(pn1, bn_g1, bn_b1, bsc, bsh);
  k_bnapply<<<16384, 256, 0, stream>>>(pn1, bsc, bsh);

  k_conv<<<dim3(32, 8, 4), 256, 0, stream>>>(pn1, post_k2, 512, 512, pn2, nullptr, nullptr);
  k_bnstats<<<512, 256, 0, stream>>>(pn2, bn_g2, bn_b2, bsc, bsh);
  k_bnapply<<<16384, 256, 0, stream>>>(pn2, bsc, bsh);

  k_conv<<<dim3(32, 8, 4), 256, 0, stream>>>(pn2, post_k3, 512, 512, pn1, nullptr, nullptr);
  k_bnstats<<<512, 256, 0, stream>>>(pn1, bn_g3, bn_b3, bsc, bsh);
  k_bnapply<<<16384, 256, 0, stream>>>(pn1, bsc, bsh);

  k_conv<<<dim3(32, 8, 4), 256, 0, stream>>>(pn1, post_k4, 512, 512, pn2, nullptr, nullptr);
  k_bnstats<<<512, 256, 0, stream>>>(pn2, bn_g4, bn_b4, bsc, bsh);
  k_bnapply<<<16384, 256, 0, stream>>>(pn2, bsc, bsh);

  k_conv<<<dim3(32, 2, 4), 256, 0, stream>>>(pn2, post_k5, 512, 80, pn1, outs_ws, outp);
}